// Round 5
// baseline (119.407 us; speedup 1.0000x reference)
//
#include <hip/hip_runtime.h>
#include <math.h>

namespace {
constexpr int D = 128;
constexpr int K = 8;
constexpr float BOUND = 3.0f;
constexpr float EPS = 1e-6f;
constexpr float MIN_BIN_W = 1e-3f;
constexpr float MIN_BIN_H = 1e-3f;
constexpr float MIN_DERIV = 1e-3f;
constexpr float LN2 = 0.6931471805599453f;
constexpr int REC = 8;           // floats per (dim,bin) record, two float4s
constexpr int S = K * REC + 4;   // 68-float row stride: 16B aligned, 8-way bank-start spread
constexpr int WPB = 8;           // waves per 512-thread block
constexpr int PPW = 4;           // row-pairs per wave (static schedule)
}

// record: ra = {icw, inv_w, d0, delta}, rb = {ich, ih, d1, E=d0+d1-2*delta}
// returns log2-domain lad contribution
__device__ __forceinline__ float spline_elem(float xv, const float* __restrict__ row,
                                             const float* kn, float* __restrict__ outp) {
    const bool inside = (xv >= -BOUND) & (xv <= BOUND);
    const float xc = fminf(fmaxf(xv, -BOUND), BOUND);
    int idx = 0;
    #pragma unroll
    for (int j = 0; j < 7; ++j) idx += (xc >= kn[j]) ? 1 : 0;
    const float4 ra = *(const float4*)(row + idx * REC);
    const float4 rb = *(const float4*)(row + idx * REC + 4);
    const float theta = (xc - ra.x) * ra.y;
    const float omt   = 1.f - theta;
    const float t1m   = theta * omt;
    const float th2   = theta * theta;
    const float num   = rb.y * (ra.w * th2 + ra.z * t1m);
    const float den   = ra.w + rb.w * t1m;
    const float rd    = __builtin_amdgcn_rcpf(den);
    const float outv  = fmaf(num, rd, rb.x);
    const float dnum  = ra.w * ra.w * (rb.z * th2 + 2.f * ra.w * t1m + ra.z * omt * omt);
    const float lad   = __log2f(dnum * rd * rd);   // (log(dnum)-2log(den))/ln2
    *outp = inside ? outv : xv;
    return inside ? lad : 0.f;
}

__global__ __launch_bounds__(512, 8) void spline_fwd(
    const float* __restrict__ x,
    const float* __restrict__ uw,
    const float* __restrict__ uh,
    const float* __restrict__ ud,
    float* __restrict__ out_u,
    float* __restrict__ out_ld,
    int nrows)
{
    __shared__ __align__(16) float s_tab[D * S];

    const int tid = threadIdx.x;
    if (tid < D) {
        const int d = tid;
        float wv[K], hv[K], cw[K + 1], ch[K + 1], der[K + 1];

        // softmax over unnormalized widths
        {
            const float* p = uw + d * K;
            float m = p[0];
            #pragma unroll
            for (int j = 1; j < K; ++j) m = fmaxf(m, p[j]);
            float s = 0.f;
            #pragma unroll
            for (int j = 0; j < K; ++j) { wv[j] = __expf(p[j] - m); s += wv[j]; }
            const float inv = __builtin_amdgcn_rcpf(s) * (1.f - MIN_BIN_W * K);
            #pragma unroll
            for (int j = 0; j < K; ++j) wv[j] = MIN_BIN_W + wv[j] * inv;
        }
        // softmax over unnormalized heights
        {
            const float* p = uh + d * K;
            float m = p[0];
            #pragma unroll
            for (int j = 1; j < K; ++j) m = fmaxf(m, p[j]);
            float s = 0.f;
            #pragma unroll
            for (int j = 0; j < K; ++j) { hv[j] = __expf(p[j] - m); s += hv[j]; }
            const float inv = __builtin_amdgcn_rcpf(s) * (1.f - MIN_BIN_H * K);
            #pragma unroll
            for (int j = 0; j < K; ++j) hv[j] = MIN_BIN_H + hv[j] * inv;
        }
        // knots (cumsum, scale to [-BOUND,BOUND], pin endpoints)
        cw[0] = -BOUND; ch[0] = -BOUND;
        float cs_w = 0.f, cs_h = 0.f;
        #pragma unroll
        for (int j = 0; j < K; ++j) {
            cs_w += wv[j]; cw[j + 1] = 2.f * BOUND * cs_w - BOUND;
            cs_h += hv[j]; ch[j + 1] = 2.f * BOUND * cs_h - BOUND;
        }
        cw[K] = BOUND; ch[K] = BOUND;

        // derivatives: softplus + MIN_DERIV, boundaries = 1 - MIN_DERIV
        der[0] = 1.f - MIN_DERIV;
        der[K] = 1.f - MIN_DERIV;
        {
            const float* p = ud + d * (K - 1);
            #pragma unroll
            for (int j = 1; j < K; ++j) {
                const float v = p[j - 1];
                const float sp = log1pf(__expf(-fabsf(v))) + fmaxf(v, 0.f);
                der[j] = MIN_DERIV + sp;
            }
        }

        // slot permutation: dim d -> slot (d&3)*32 + (d>>2); a lane's 4 dims sit at
        // lane-stride-1 slots => 68-dword lane stride => 8-way bank-start spread
        float* row = s_tab + ((d & 3) * 32 + (d >> 2)) * S;
        #pragma unroll
        for (int j = 0; j < K; ++j) {
            const float w  = cw[j + 1] - cw[j];
            const float h  = ch[j + 1] - ch[j];
            const float iw = 1.f / w;
            const float dl = h * iw;
            row[j * REC + 0] = cw[j];
            row[j * REC + 1] = iw;
            row[j * REC + 2] = der[j];
            row[j * REC + 3] = dl;
            row[j * REC + 4] = ch[j];
            row[j * REC + 5] = h;
            row[j * REC + 6] = der[j + 1];
            row[j * REC + 7] = der[j] + der[j + 1] - 2.f * dl;
        }
    }
    __syncthreads();

    const int wave = tid >> 6;
    const int lane = tid & 63;
    const int l32  = lane & 31;
    const int half = lane >> 5;          // row 2p (lanes 0-31) or 2p+1 (lanes 32-63)

    // this lane's 4 dims are 4*l32 + c, living at slots c*32 + l32
    const float* rowp0 = s_tab + (0 * 32 + l32) * S;
    const float* rowp1 = s_tab + (1 * 32 + l32) * S;
    const float* rowp2 = s_tab + (2 * 32 + l32) * S;
    const float* rowp3 = s_tab + (3 * 32 + l32) * S;

    // interior knots (+EPS folded) in registers: icw of bin j+1 IS interior knot j
    float kn[28];
    #pragma unroll
    for (int j = 0; j < 7; ++j) {
        kn[j]      = rowp0[(j + 1) * REC] + EPS;
        kn[7 + j]  = rowp1[(j + 1) * REC] + EPS;
        kn[14 + j] = rowp2[(j + 1) * REC] + EPS;
        kn[21 + j] = rowp3[(j + 1) * REC] + EPS;
    }

    const int p0 = (blockIdx.x * WPB + wave) * PPW;   // grid sized so p0+PPW <= npairs
    const int lo4 = lane << 2;

    // software pipeline: one pair-load in flight ahead of compute
    float4 xcur = *(const float4*)(x + (size_t)(p0 * 2) * D + lo4);
    #pragma unroll
    for (int c = 0; c < PPW; ++c) {
        const int p = p0 + c;
        float4 xnext;
        if (c + 1 < PPW)
            xnext = *(const float4*)(x + (size_t)((p + 1) * 2) * D + lo4);

        float4 u;
        float la;
        la  = spline_elem(xcur.x, rowp0, kn +  0, &u.x);
        la += spline_elem(xcur.y, rowp1, kn +  7, &u.y);
        la += spline_elem(xcur.z, rowp2, kn + 14, &u.z);
        la += spline_elem(xcur.w, rowp3, kn + 21, &u.w);

        *(float4*)(out_u + (size_t)(p * 2) * D + lo4) = u;

        // butterfly within each 32-lane half: both rows of the pair at once
        la += __shfl_xor(la, 1);
        la += __shfl_xor(la, 2);
        la += __shfl_xor(la, 4);
        la += __shfl_xor(la, 8);
        la += __shfl_xor(la, 16);
        if (l32 == 0) out_ld[p * 2 + half] = la * LN2;

        xcur = xnext;
    }
}

extern "C" void kernel_launch(void* const* d_in, const int* in_sizes, int n_in,
                              void* d_out, int out_size, void* d_ws, size_t ws_size,
                              hipStream_t stream) {
    const float* x  = (const float*)d_in[0];
    const float* uw = (const float*)d_in[1];
    const float* uh = (const float*)d_in[2];
    const float* ud = (const float*)d_in[3];
    const int nrows = in_sizes[0] / D;
    float* out_u  = (float*)d_out;
    float* out_ld = (float*)d_out + (size_t)nrows * D;
    // 65536 rows = 32768 pairs = 1024 blocks x 8 waves x 4 pairs, exact.
    // 1024 blocks x 512 thr @34.8KB LDS = 4 blocks/CU, 32 waves/CU, fully resident.
    const int npairs = nrows / 2;
    const int nblocks = (npairs + WPB * PPW - 1) / (WPB * PPW);
    spline_fwd<<<nblocks, 512, 0, stream>>>(x, uw, uh, ud, out_u, out_ld, nrows);
}

// Round 6
// 100.091 us; speedup vs baseline: 1.1930x; 1.1930x over previous
//
#include <hip/hip_runtime.h>
#include <math.h>

namespace {
constexpr int D = 128;
constexpr int K = 8;
constexpr float BOUND = 3.0f;
constexpr float EPS = 1e-6f;
constexpr float MIN_BIN_W = 1e-3f;
constexpr float MIN_BIN_H = 1e-3f;
constexpr float MIN_DERIV = 1e-3f;
constexpr float LN2 = 0.6931471805599453f;
constexpr int WPB = 8;           // waves per 512-thread block
constexpr int RPW = 8;           // rows per wave (static schedule)
}

// Bin-major tables: A[bin][slot] = {icw, inv_w, d0, delta}, B[bin][slot] = {ich, ih, d1, E}.
// Gather dword addr = idx*512 + slot*4: idx*512 == 0 (mod 32) -> bank independent of idx;
// slot in {lane, 64+lane} -> start bank 4*lane mod 32 tiles all 32 banks -> conflict-free.
__device__ __forceinline__ float spline_elem(float xv, int slot, const float* kn,
                                             const float4* __restrict__ A,
                                             const float4* __restrict__ B,
                                             float* __restrict__ outp) {
    const bool inside = (xv >= -BOUND) & (xv <= BOUND);
    const float xc = fminf(fmaxf(xv, -BOUND), BOUND);
    int idx = 0;
    #pragma unroll
    for (int j = 0; j < 7; ++j) idx += (xc >= kn[j]) ? 1 : 0;
    const float4 ra = A[idx * D + slot];
    const float4 rb = B[idx * D + slot];
    const float theta = (xc - ra.x) * ra.y;
    const float omt   = 1.f - theta;
    const float t1m   = theta * omt;
    const float th2   = theta * theta;
    const float num   = rb.y * (ra.w * th2 + ra.z * t1m);
    const float den   = ra.w + rb.w * t1m;
    const float rd    = __builtin_amdgcn_rcpf(den);
    const float outv  = fmaf(num, rd, rb.x);
    const float dnum  = ra.w * ra.w * (rb.z * th2 + 2.f * ra.w * t1m + ra.z * omt * omt);
    const float lad   = __log2f(dnum * rd * rd);   // (log(dnum)-2log(den))/ln2
    *outp = inside ? outv : xv;
    return inside ? lad : 0.f;
}

__global__ __launch_bounds__(512, 6) void spline_fwd(
    const float* __restrict__ x,
    const float* __restrict__ uw,
    const float* __restrict__ uh,
    const float* __restrict__ ud,
    float* __restrict__ out_u,
    float* __restrict__ out_ld,
    int nrows)
{
    __shared__ __align__(16) float4 s_A[K * D];   // 16 KB
    __shared__ __align__(16) float4 s_B[K * D];   // 16 KB

    const int tid = threadIdx.x;
    if (tid < D) {
        const int d = tid;
        float wv[K], hv[K], cw[K + 1], ch[K + 1], der[K + 1];

        // softmax over unnormalized widths
        {
            const float* p = uw + d * K;
            float m = p[0];
            #pragma unroll
            for (int j = 1; j < K; ++j) m = fmaxf(m, p[j]);
            float s = 0.f;
            #pragma unroll
            for (int j = 0; j < K; ++j) { wv[j] = __expf(p[j] - m); s += wv[j]; }
            const float inv = (1.f - MIN_BIN_W * K) / s;
            #pragma unroll
            for (int j = 0; j < K; ++j) wv[j] = MIN_BIN_W + wv[j] * inv;
        }
        // softmax over unnormalized heights
        {
            const float* p = uh + d * K;
            float m = p[0];
            #pragma unroll
            for (int j = 1; j < K; ++j) m = fmaxf(m, p[j]);
            float s = 0.f;
            #pragma unroll
            for (int j = 0; j < K; ++j) { hv[j] = __expf(p[j] - m); s += hv[j]; }
            const float inv = (1.f - MIN_BIN_H * K) / s;
            #pragma unroll
            for (int j = 0; j < K; ++j) hv[j] = MIN_BIN_H + hv[j] * inv;
        }
        // knots (cumsum, scale to [-BOUND,BOUND], pin endpoints)
        cw[0] = -BOUND; ch[0] = -BOUND;
        float cs_w = 0.f, cs_h = 0.f;
        #pragma unroll
        for (int j = 0; j < K; ++j) {
            cs_w += wv[j]; cw[j + 1] = 2.f * BOUND * cs_w - BOUND;
            cs_h += hv[j]; ch[j + 1] = 2.f * BOUND * cs_h - BOUND;
        }
        cw[K] = BOUND; ch[K] = BOUND;

        // derivatives: softplus + MIN_DERIV, boundaries = 1 - MIN_DERIV
        der[0] = 1.f - MIN_DERIV;
        der[K] = 1.f - MIN_DERIV;
        {
            const float* p = ud + d * (K - 1);
            #pragma unroll
            for (int j = 1; j < K; ++j) {
                const float v = p[j - 1];
                const float sp = log1pf(__expf(-fabsf(v))) + fmaxf(v, 0.f);
                der[j] = MIN_DERIV + sp;
            }
        }

        // dim d -> slot (d&1)*64 + (d>>1): lane l's dims 2l,2l+1 live at slots l, 64+l
        const int slot = (d & 1) * 64 + (d >> 1);
        #pragma unroll
        for (int j = 0; j < K; ++j) {
            const float w  = cw[j + 1] - cw[j];
            const float h  = ch[j + 1] - ch[j];
            const float iw = 1.f / w;
            const float dl = h * iw;
            s_A[j * D + slot] = make_float4(cw[j], iw, der[j], dl);
            s_B[j * D + slot] = make_float4(ch[j], h, der[j + 1],
                                            der[j] + der[j + 1] - 2.f * dl);
        }
    }
    __syncthreads();

    const int wave = tid >> 6;
    const int lane = tid & 63;
    const int slot0 = lane;        // dim 2*lane
    const int slot1 = 64 + lane;   // dim 2*lane + 1

    // interior knots (+EPS folded): icw of bin j+1 IS interior knot j
    float kn0[7], kn1[7];
    #pragma unroll
    for (int j = 0; j < 7; ++j) {
        kn0[j] = s_A[(j + 1) * D + slot0].x + EPS;
        kn1[j] = s_A[(j + 1) * D + slot1].x + EPS;
    }

    const int r0 = (blockIdx.x * WPB + wave) * RPW;
    const int lo2 = lane * 2;

    #pragma unroll
    for (int i = 0; i < RPW; ++i) {
        const int r = r0 + i;
        if (r < nrows) {
            const float2 xv = *(const float2*)(x + (size_t)r * D + lo2);
            float u0, u1;
            float la = spline_elem(xv.x, slot0, kn0, s_A, s_B, &u0)
                     + spline_elem(xv.y, slot1, kn1, s_A, s_B, &u1);
            *(float2*)(out_u + (size_t)r * D + lo2) = make_float2(u0, u1);

            // full-wave butterfly: all 64 lanes hold the row sum afterwards
            la += __shfl_xor(la, 1);
            la += __shfl_xor(la, 2);
            la += __shfl_xor(la, 4);
            la += __shfl_xor(la, 8);
            la += __shfl_xor(la, 16);
            la += __shfl_xor(la, 32);
            if (lane == 0) out_ld[r] = la * LN2;
        }
    }
}

extern "C" void kernel_launch(void* const* d_in, const int* in_sizes, int n_in,
                              void* d_out, int out_size, void* d_ws, size_t ws_size,
                              hipStream_t stream) {
    const float* x  = (const float*)d_in[0];
    const float* uw = (const float*)d_in[1];
    const float* uh = (const float*)d_in[2];
    const float* ud = (const float*)d_in[3];
    const int nrows = in_sizes[0] / D;
    float* out_u  = (float*)d_out;
    float* out_ld = (float*)d_out + (size_t)nrows * D;
    // 65536 rows = 1024 blocks x 8 waves x 8 rows, exact; 32 KB LDS ->
    // 4 blocks/CU if VGPR <= 64 (kn[14] + float2 state is sized to fit)
    const int nblocks = (nrows + WPB * RPW - 1) / (WPB * RPW);
    spline_fwd<<<nblocks, 512, 0, stream>>>(x, uw, uh, ud, out_u, out_ld, nrows);
}

// Round 7
// 96.915 us; speedup vs baseline: 1.2321x; 1.0328x over previous
//
#include <hip/hip_runtime.h>
#include <math.h>

namespace {
constexpr int D = 128;
constexpr int K = 8;
constexpr float BOUND = 3.0f;
constexpr float EPS = 1e-6f;
constexpr float MIN_BIN_W = 1e-3f;
constexpr float MIN_BIN_H = 1e-3f;
constexpr float MIN_DERIV = 1e-3f;
constexpr float LN2 = 0.6931471805599453f;
constexpr int WPB = 8;           // waves per 512-thread block
constexpr int RPW = 8;           // rows per wave (static schedule, exact grid)
}

// one v_add_f32 with a DPP-modified operand; masked-off rows add 0
template <int CTRL, int ROWM>
__device__ __forceinline__ float dpp_add(float v) {
    const int t = __builtin_amdgcn_update_dpp(0, __float_as_int(v), CTRL, ROWM, 0xf, true);
    return v + __int_as_float(t);
}

// full wave64 sum, result valid in lane 63 (VALU only, no LDS pipe)
__device__ __forceinline__ float wave_sum_dpp(float v) {
    v = dpp_add<0x111, 0xf>(v);   // row_shr:1
    v = dpp_add<0x112, 0xf>(v);   // row_shr:2
    v = dpp_add<0x114, 0xf>(v);   // row_shr:4
    v = dpp_add<0x118, 0xf>(v);   // row_shr:8   -> lane 15/31/47/63 hold row16 sums
    v = dpp_add<0x142, 0xa>(v);   // row_bcast:15, rows 1,3 -> lane31, lane63 hold half sums
    v = dpp_add<0x143, 0xc>(v);   // row_bcast:31, rows 2,3 -> lane63 holds full sum
    return v;
}

// Bin-major tables: A[bin][slot] = {icw, inv_w, d0, delta}, B[bin][slot] = {ich, ih, d1, E}.
// Gather dword addr = idx*512 + slot*4: idx term == 0 (mod 32) -> bank independent of idx;
// slot in {lane, 64+lane} tiles all 32 banks -> conflict-free b128 gathers.
__device__ __forceinline__ float spline_elem(float xv, int slot, const float* kn,
                                             const float4* __restrict__ A,
                                             const float4* __restrict__ B,
                                             float* __restrict__ outp) {
    const bool inside = (xv >= -BOUND) & (xv <= BOUND);
    const float xc = fminf(fmaxf(xv, -BOUND), BOUND);
    int idx = 0;
    #pragma unroll
    for (int j = 0; j < 7; ++j) idx += (xc >= kn[j]) ? 1 : 0;
    const float4 ra = A[idx * D + slot];
    const float4 rb = B[idx * D + slot];
    const float theta = (xc - ra.x) * ra.y;
    const float omt   = 1.f - theta;
    const float t1m   = theta * omt;
    const float th2   = theta * theta;
    const float num   = rb.y * (ra.w * th2 + ra.z * t1m);
    const float den   = ra.w + rb.w * t1m;
    const float rd    = __builtin_amdgcn_rcpf(den);
    const float outv  = fmaf(num, rd, rb.x);
    const float dnum  = ra.w * ra.w * (rb.z * th2 + 2.f * ra.w * t1m + ra.z * omt * omt);
    const float lad   = __log2f(dnum * rd * rd);   // (log(dnum)-2log(den))/ln2
    *outp = inside ? outv : xv;
    return inside ? lad : 0.f;
}

__global__ __launch_bounds__(512, 6) void spline_fwd(
    const float* __restrict__ x,
    const float* __restrict__ uw,
    const float* __restrict__ uh,
    const float* __restrict__ ud,
    float* __restrict__ out_u,
    float* __restrict__ out_ld,
    int nrows)
{
    __shared__ __align__(16) float4 s_A[K * D];   // 16 KB
    __shared__ __align__(16) float4 s_B[K * D];   // 16 KB

    const int tid = threadIdx.x;
    if (tid < D) {
        const int d = tid;
        float wv[K], hv[K], cw[K + 1], ch[K + 1], der[K + 1];

        // softmax over unnormalized widths
        {
            const float* p = uw + d * K;
            float m = p[0];
            #pragma unroll
            for (int j = 1; j < K; ++j) m = fmaxf(m, p[j]);
            float s = 0.f;
            #pragma unroll
            for (int j = 0; j < K; ++j) { wv[j] = __expf(p[j] - m); s += wv[j]; }
            const float inv = (1.f - MIN_BIN_W * K) / s;
            #pragma unroll
            for (int j = 0; j < K; ++j) wv[j] = MIN_BIN_W + wv[j] * inv;
        }
        // softmax over unnormalized heights
        {
            const float* p = uh + d * K;
            float m = p[0];
            #pragma unroll
            for (int j = 1; j < K; ++j) m = fmaxf(m, p[j]);
            float s = 0.f;
            #pragma unroll
            for (int j = 0; j < K; ++j) { hv[j] = __expf(p[j] - m); s += hv[j]; }
            const float inv = (1.f - MIN_BIN_H * K) / s;
            #pragma unroll
            for (int j = 0; j < K; ++j) hv[j] = MIN_BIN_H + hv[j] * inv;
        }
        // knots (cumsum, scale to [-BOUND,BOUND], pin endpoints)
        cw[0] = -BOUND; ch[0] = -BOUND;
        float cs_w = 0.f, cs_h = 0.f;
        #pragma unroll
        for (int j = 0; j < K; ++j) {
            cs_w += wv[j]; cw[j + 1] = 2.f * BOUND * cs_w - BOUND;
            cs_h += hv[j]; ch[j + 1] = 2.f * BOUND * cs_h - BOUND;
        }
        cw[K] = BOUND; ch[K] = BOUND;

        // derivatives: softplus + MIN_DERIV, boundaries = 1 - MIN_DERIV
        der[0] = 1.f - MIN_DERIV;
        der[K] = 1.f - MIN_DERIV;
        {
            const float* p = ud + d * (K - 1);
            #pragma unroll
            for (int j = 1; j < K; ++j) {
                const float v = p[j - 1];
                const float sp = log1pf(__expf(-fabsf(v))) + fmaxf(v, 0.f);
                der[j] = MIN_DERIV + sp;
            }
        }

        // dim d -> slot (d&1)*64 + (d>>1): lane l's dims 2l,2l+1 live at slots l, 64+l
        const int slot = (d & 1) * 64 + (d >> 1);
        #pragma unroll
        for (int j = 0; j < K; ++j) {
            const float w  = cw[j + 1] - cw[j];
            const float h  = ch[j + 1] - ch[j];
            const float iw = 1.f / w;
            const float dl = h * iw;
            s_A[j * D + slot] = make_float4(cw[j], iw, der[j], dl);
            s_B[j * D + slot] = make_float4(ch[j], h, der[j + 1],
                                            der[j] + der[j + 1] - 2.f * dl);
        }
    }
    __syncthreads();

    const int wave = tid >> 6;
    const int lane = tid & 63;
    const int slot0 = lane;        // dim 2*lane
    const int slot1 = 64 + lane;   // dim 2*lane + 1

    // interior knots (+EPS folded): icw of bin j+1 IS interior knot j
    float kn0[7], kn1[7];
    #pragma unroll
    for (int j = 0; j < 7; ++j) {
        kn0[j] = s_A[(j + 1) * D + slot0].x + EPS;
        kn1[j] = s_A[(j + 1) * D + slot1].x + EPS;
    }

    const int r0 = (blockIdx.x * WPB + wave) * RPW;   // grid exact: no guards
    const int lo2 = lane * 2;

    #pragma unroll
    for (int i = 0; i < RPW; ++i) {
        const int r = r0 + i;
        const float2 xv = *(const float2*)(x + (size_t)r * D + lo2);
        float u0, u1;
        float la = spline_elem(xv.x, slot0, kn0, s_A, s_B, &u0)
                 + spline_elem(xv.y, slot1, kn1, s_A, s_B, &u1);
        *(float2*)(out_u + (size_t)r * D + lo2) = make_float2(u0, u1);

        la = wave_sum_dpp(la);            // VALU-only reduction, sum lands in lane 63
        if (lane == 63) out_ld[r] = la * LN2;
    }
}

extern "C" void kernel_launch(void* const* d_in, const int* in_sizes, int n_in,
                              void* d_out, int out_size, void* d_ws, size_t ws_size,
                              hipStream_t stream) {
    const float* x  = (const float*)d_in[0];
    const float* uw = (const float*)d_in[1];
    const float* uh = (const float*)d_in[2];
    const float* ud = (const float*)d_in[3];
    const int nrows = in_sizes[0] / D;
    float* out_u  = (float*)d_out;
    float* out_ld = (float*)d_out + (size_t)nrows * D;
    // 65536 rows = 1024 blocks x 8 waves x 8 rows, exact
    const int nblocks = nrows / (WPB * RPW);
    spline_fwd<<<nblocks, 512, 0, stream>>>(x, uw, uh, ud, out_u, out_ld, nrows);
}

// Round 8
// 96.290 us; speedup vs baseline: 1.2401x; 1.0065x over previous
//
#include <hip/hip_runtime.h>
#include <math.h>

namespace {
constexpr int D = 128;
constexpr int K = 8;
constexpr float BOUND = 3.0f;
constexpr float EPS = 1e-6f;
constexpr float MIN_BIN_W = 1e-3f;
constexpr float MIN_BIN_H = 1e-3f;
constexpr float MIN_DERIV = 1e-3f;
constexpr float LN2 = 0.6931471805599453f;
constexpr int WPB = 8;           // waves per 512-thread block
constexpr int RPW = 8;           // rows per wave (static schedule, exact grid)
}

typedef float v2f __attribute__((ext_vector_type(2)));

// one v_add_f32 with a DPP-modified operand; shifted-in lanes contribute 0
template <int CTRL, int ROWM>
__device__ __forceinline__ float dpp_add(float v) {
    const int t = __builtin_amdgcn_update_dpp(0, __float_as_int(v), CTRL, ROWM, 0xf, true);
    return v + __int_as_float(t);
}

// full wave64 sum, result valid in lane 63 (VALU only, no LDS pipe)
__device__ __forceinline__ float wave_sum_dpp(float v) {
    v = dpp_add<0x111, 0xf>(v);   // row_shr:1
    v = dpp_add<0x112, 0xf>(v);   // row_shr:2
    v = dpp_add<0x114, 0xf>(v);   // row_shr:4
    v = dpp_add<0x118, 0xf>(v);   // row_shr:8
    v = dpp_add<0x142, 0xa>(v);   // row_bcast:15 -> lanes 31, 63
    v = dpp_add<0x143, 0xc>(v);   // row_bcast:31 -> lane 63
    return v;
}

__global__ __launch_bounds__(512, 6) void spline_fwd(
    const float* __restrict__ x,
    const float* __restrict__ uw,
    const float* __restrict__ uh,
    const float* __restrict__ ud,
    float* __restrict__ out_u,
    float* __restrict__ out_ld,
    int nrows)
{
    // combined bin-major table: A-half [bin*D+slot] = {icw, inv_w, d0, delta},
    // B-half at +K*D (byte offset 16384, fits ds_read offset imm) = {ich, ih, d1, E}.
    // Gather dword addr = idx*512 + slot*4: idx term == 0 (mod 32) -> bank
    // independent of idx; slots {lane, 64+lane} tile all 32 banks -> conflict-free.
    __shared__ __align__(16) float4 s_T[2 * K * D];   // 32 KB

    const int tid = threadIdx.x;
    if (tid < D) {
        const int d = tid;
        float wv[K], hv[K], cw[K + 1], ch[K + 1], der[K + 1];

        {   // softmax over unnormalized widths
            const float* p = uw + d * K;
            float m = p[0];
            #pragma unroll
            for (int j = 1; j < K; ++j) m = fmaxf(m, p[j]);
            float s = 0.f;
            #pragma unroll
            for (int j = 0; j < K; ++j) { wv[j] = __expf(p[j] - m); s += wv[j]; }
            const float inv = (1.f - MIN_BIN_W * K) / s;
            #pragma unroll
            for (int j = 0; j < K; ++j) wv[j] = MIN_BIN_W + wv[j] * inv;
        }
        {   // softmax over unnormalized heights
            const float* p = uh + d * K;
            float m = p[0];
            #pragma unroll
            for (int j = 1; j < K; ++j) m = fmaxf(m, p[j]);
            float s = 0.f;
            #pragma unroll
            for (int j = 0; j < K; ++j) { hv[j] = __expf(p[j] - m); s += hv[j]; }
            const float inv = (1.f - MIN_BIN_H * K) / s;
            #pragma unroll
            for (int j = 0; j < K; ++j) hv[j] = MIN_BIN_H + hv[j] * inv;
        }
        // knots (cumsum, scale to [-BOUND,BOUND], pin endpoints)
        cw[0] = -BOUND; ch[0] = -BOUND;
        float cs_w = 0.f, cs_h = 0.f;
        #pragma unroll
        for (int j = 0; j < K; ++j) {
            cs_w += wv[j]; cw[j + 1] = 2.f * BOUND * cs_w - BOUND;
            cs_h += hv[j]; ch[j + 1] = 2.f * BOUND * cs_h - BOUND;
        }
        cw[K] = BOUND; ch[K] = BOUND;

        // derivatives: softplus + MIN_DERIV, boundaries = 1 - MIN_DERIV
        der[0] = 1.f - MIN_DERIV;
        der[K] = 1.f - MIN_DERIV;
        {
            const float* p = ud + d * (K - 1);
            #pragma unroll
            for (int j = 1; j < K; ++j) {
                const float v = p[j - 1];
                const float sp = log1pf(__expf(-fabsf(v))) + fmaxf(v, 0.f);
                der[j] = MIN_DERIV + sp;
            }
        }

        // dim d -> slot (d&1)*64 + (d>>1): lane l's dims 2l,2l+1 live at slots l, 64+l
        const int slot = (d & 1) * 64 + (d >> 1);
        #pragma unroll
        for (int j = 0; j < K; ++j) {
            const float w  = cw[j + 1] - cw[j];
            const float h  = ch[j + 1] - ch[j];
            const float iw = 1.f / w;
            const float dl = h * iw;
            s_T[j * D + slot] = make_float4(cw[j], iw, der[j], dl);
            s_T[K * D + j * D + slot] = make_float4(ch[j], h, der[j + 1],
                                                    der[j] + der[j + 1] - 2.f * dl);
        }
    }
    __syncthreads();

    const int wave = tid >> 6;
    const int lane = tid & 63;
    const int slot0 = lane;        // dim 2*lane
    const int slot1 = 64 + lane;   // dim 2*lane + 1
    const float4* __restrict__ pa0 = s_T + slot0;
    const float4* __restrict__ pa1 = s_T + slot1;

    // interior knots (+EPS folded): icw of bin j+1 IS interior knot j
    float kn0[7], kn1[7];
    #pragma unroll
    for (int j = 0; j < 7; ++j) {
        kn0[j] = pa0[(j + 1) * D].x + EPS;
        kn1[j] = pa1[(j + 1) * D].x + EPS;
    }

    const int r0 = (blockIdx.x * WPB + wave) * RPW;   // grid exact: no guards
    const int lo2 = lane * 2;
    const float* __restrict__ xbase = x + (size_t)r0 * D + lo2;
    float* __restrict__ ubase = out_u + (size_t)r0 * D + lo2;

    // prefetch all 8 row-loads up front (independent, stay in flight)
    float2 xs[RPW];
    #pragma unroll
    for (int i = 0; i < RPW; ++i)
        xs[i] = *(const float2*)(xbase + (size_t)i * D);

    #pragma unroll
    for (int i = 0; i < RPW; ++i) {
        const float xv0 = xs[i].x, xv1 = xs[i].y;
        const float xc0 = fminf(fmaxf(xv0, -BOUND), BOUND);
        const float xc1 = fminf(fmaxf(xv1, -BOUND), BOUND);
        const bool in0 = fabsf(xv0) <= BOUND;
        const bool in1 = fabsf(xv1) <= BOUND;

        int i0 = 0, i1 = 0;
        #pragma unroll
        for (int j = 0; j < 7; ++j) {
            i0 += (xc0 >= kn0[j]) ? 1 : 0;
            i1 += (xc1 >= kn1[j]) ? 1 : 0;
        }

        const float4 ra0 = pa0[i0 * D];
        const float4 rb0 = pa0[i0 * D + K * D];   // same vaddr, +16384 imm
        const float4 ra1 = pa1[i1 * D];
        const float4 rb1 = pa1[i1 * D + K * D];

        // packed-FP32 polynomial: both elements in one v_pk_* stream
        const v2f xc  = {xc0, xc1};
        const v2f xw  = {xv0, xv1};
        const v2f icw = {ra0.x, ra1.x}, inw = {ra0.y, ra1.y};
        const v2f d0  = {ra0.z, ra1.z}, dl  = {ra0.w, ra1.w};
        const v2f ich = {rb0.x, rb1.x}, ih  = {rb0.y, rb1.y};
        const v2f d1  = {rb0.z, rb1.z}, E   = {rb0.w, rb1.w};

        const v2f theta = (xc - icw) * inw;
        const v2f omt   = (v2f)1.f - theta;
        const v2f t1m   = theta * omt;
        const v2f th2   = theta * theta;
        const v2f num   = ih * (dl * th2 + d0 * t1m);
        const v2f den   = dl + E * t1m;
        const v2f rd    = {__builtin_amdgcn_rcpf(den.x), __builtin_amdgcn_rcpf(den.y)};
        const v2f outv  = num * rd + ich;
        const v2f dnum  = (dl * dl) * (d1 * th2 + (dl + dl) * t1m + d0 * (omt * omt));
        const v2f P     = dnum * (rd * rd);

        // tail blend is exact: spline maps clamped boundary to +/-BOUND exactly
        const v2f u = outv + (xw - xc);
        *(float2*)(ubase + (size_t)i * D) = make_float2(u.x, u.y);

        // one log per lane-row: lad0+lad1 = log2(P0*P1), outside elems -> P=1
        const float P0 = in0 ? P.x : 1.f;
        const float P1 = in1 ? P.y : 1.f;
        float la = __log2f(P0 * P1);

        la = wave_sum_dpp(la);
        if (lane == 63) out_ld[r0 + i] = la * LN2;
    }
}

extern "C" void kernel_launch(void* const* d_in, const int* in_sizes, int n_in,
                              void* d_out, int out_size, void* d_ws, size_t ws_size,
                              hipStream_t stream) {
    const float* x  = (const float*)d_in[0];
    const float* uw = (const float*)d_in[1];
    const float* uh = (const float*)d_in[2];
    const float* ud = (const float*)d_in[3];
    const int nrows = in_sizes[0] / D;
    float* out_u  = (float*)d_out;
    float* out_ld = (float*)d_out + (size_t)nrows * D;
    // 65536 rows = 1024 blocks x 8 waves x 8 rows, exact
    const int nblocks = nrows / (WPB * RPW);
    spline_fwd<<<nblocks, 512, 0, stream>>>(x, uw, uh, ud, out_u, out_ld, nrows);
}